// Round 3
// 683.289 us; speedup vs baseline: 1.0699x; 1.0699x over previous
//
#include <hip/hip_runtime.h>

typedef _Float16 half8 __attribute__((ext_vector_type(8)));
typedef float floatx4 __attribute__((ext_vector_type(4)));

#define CIN 32
#define COUT 32
#define KOFF 27
#define EPSV 1e-5f

// ---------------------------------------------------------------------------
// ws layout:
//   [0, (N+1)*32*2)        feats16 (f16 copy of feats + zero row at index N)
//   [+, +55296)            Wpack: B-fragments, f16
//   [align 512, +768)      stats: sum[32], sumsq[32], flag
//   [align 256, +N*4)      mpack: 27-bit validity mask per voxel
// conv reads nidx in natural [N][27] layout directly (L1/L2-hot, reused 27x);
// invalid neighbors redirect to the zero row -> all gathers UNCONDITIONAL so
// the compiler can software-pipeline with counted vmcnt (no vmcnt(0) drain).
// Dispatches: memset, setup(pack_w+detect), prep(cvt+zero-row+maskpack),
//             conv(+fused BN stats), bn_apply(+inline finalize).
// ---------------------------------------------------------------------------

// blocks 0..26: pack W fragments; block 27: detect mask dtype.
__global__ void setup_k(const float* __restrict__ W, _Float16* __restrict__ wp,
                        const unsigned char* __restrict__ m,
                        int* __restrict__ flag) {
  if (blockIdx.x < KOFF) {
    int ko = blockIdx.x;
    int h = threadIdx.x >> 6;        // 128 threads: 2 halves
    int lane = threadIdx.x & 63;
    int col = lane & 15, quad = lane >> 4;
    half8 p;
#pragma unroll
    for (int j = 0; j < 8; ++j) {
      int k = quad * 8 + j;
      p[j] = (_Float16)W[(ko * CIN + k) * COUT + h * 16 + col];
    }
    *(half8*)(wp + ((size_t)(ko * 2 + h) * 64 + lane) * 8) = p;
  } else {
    // int32 mask => bytes at offset%4!=0 all zero; byte mask => ~50% nonzero
    int tid = threadIdx.x;
    int any = 0;
    for (int i = tid; i < 4096; i += 128) {
      if ((i & 3) != 0 && m[i] != 0) any = 1;
    }
    if (any) atomicOr(flag, 1);
  }
}

// blocks [0,cvtBlocks): feats fp32->f16 (+ zero row at index N).
// blocks [cvtBlocks,..): build 27-bit mask pack per voxel.
__global__ void prep_k(const float* __restrict__ feats,
                       _Float16* __restrict__ f16, int total8,
                       const unsigned char* __restrict__ nmask,
                       const int* __restrict__ flagp,
                       unsigned int* __restrict__ mpack, int N,
                       int cvtBlocks) {
  int tid = threadIdx.x;
  if ((int)blockIdx.x < cvtBlocks) {
    int t = blockIdx.x * 256 + tid;
    if (t < total8) {
      const floatx4* in4 = (const floatx4*)feats;
      floatx4 a = __builtin_nontemporal_load(&in4[(size_t)t * 2]);
      floatx4 b = __builtin_nontemporal_load(&in4[(size_t)t * 2 + 1]);
      half8 h;
      h[0] = (_Float16)a[0]; h[1] = (_Float16)a[1];
      h[2] = (_Float16)a[2]; h[3] = (_Float16)a[3];
      h[4] = (_Float16)b[0]; h[5] = (_Float16)b[1];
      h[6] = (_Float16)b[2]; h[7] = (_Float16)b[3];
      *(half8*)(f16 + (size_t)t * 8) = h;  // temporal: keep cache-resident
    } else if (t < total8 + 4) {
      half8 z;
#pragma unroll
      for (int j = 0; j < 8; ++j) z[j] = (_Float16)0.f;
      *(half8*)(f16 + (size_t)t * 8) = z;  // zero row at voxel index N
    }
  } else {
    int vox = (blockIdx.x - cvtBlocks) * 256 + tid;
    if (vox >= N) return;
    unsigned int mk = 0;
    if (*flagp != 0) {
      const unsigned char* p = nmask + (size_t)vox * KOFF;
#pragma unroll
      for (int ko = 0; ko < KOFF; ++ko)
        mk |= (p[ko] != 0 ? 1u : 0u) << ko;
    } else {
      const int* p = (const int*)nmask + (size_t)vox * KOFF;
#pragma unroll
      for (int ko = 0; ko < KOFF; ++ko)
        mk |= (p[ko] != 0 ? 1u : 0u) << ko;
    }
    mpack[vox] = mk;
  }
}

__launch_bounds__(256, 3)
__global__ void conv_mfma_d(const _Float16* __restrict__ f16,
                            const _Float16* __restrict__ wp,
                            const int* __restrict__ nidx,
                            const unsigned int* __restrict__ mpack,
                            float* __restrict__ y,
                            float* __restrict__ stats, int N) {
  __shared__ float smS[4 * 32];
  __shared__ float smQ[4 * 32];
  int wave = threadIdx.x >> 6;
  int lane = threadIdx.x & 63;
  int base = (blockIdx.x * 4 + wave) * 64;
  bool active = base < N;
  int col = lane & 15, quad = lane >> 4;
  const half8* wfrag = (const half8*)wp;
  const _Float16* fq = f16 + quad * 8;  // per-quad 16B slice of a 64B row

  floatx4 acc[4][2];
#pragma unroll
  for (int t = 0; t < 4; ++t)
#pragma unroll
    for (int h = 0; h < 2; ++h) {
      acc[t][h][0] = 0.f; acc[t][h][1] = 0.f;
      acc[t][h][2] = 0.f; acc[t][h][3] = 0.f;
    }

  if (active) {
    unsigned int mp[4];
    int o27[4];
#pragma unroll
    for (int t = 0; t < 4; ++t) {
      int vox = base + t * 16 + col;
      if (vox > N - 1) vox = N - 1;  // defensive clamp (no-op when 64|N)
      o27[t] = vox * KOFF;
      mp[t] = mpack[vox];
    }
    // idx pipeline: ivB holds idx[ko+1]; ivN prefetches idx[ko+2]
    int ivB[4];
    half8 aC[4];
#pragma unroll
    for (int t = 0; t < 4; ++t) {
      int iv0 = nidx[o27[t]];
      int sel = (mp[t] & 1u) ? iv0 : N;
      aC[t] = *(const half8*)(fq + ((size_t)sel << 5));
    }
#pragma unroll
    for (int t = 0; t < 4; ++t) ivB[t] = nidx[o27[t] + 1];
    half8 bC0 = wfrag[lane];
    half8 bC1 = wfrag[64 + lane];

#pragma unroll
    for (int ko = 0; ko < KOFF; ++ko) {
      int ivN[4];
      if (ko + 2 < KOFF) {
#pragma unroll
        for (int t = 0; t < 4; ++t) ivN[t] = nidx[o27[t] + ko + 2];
      }
      half8 bN0, bN1;
      if (ko + 1 < KOFF) {
        bN0 = wfrag[(size_t)((ko + 1) * 2 + 0) * 64 + lane];
        bN1 = wfrag[(size_t)((ko + 1) * 2 + 1) * 64 + lane];
      }
      half8 aN[4];
      if (ko + 1 < KOFF) {
#pragma unroll
        for (int t = 0; t < 4; ++t) {
          int sel = ((mp[t] >> (ko + 1)) & 1u) ? ivB[t] : N;
          aN[t] = *(const half8*)(fq + ((size_t)sel << 5));
        }
      }
#pragma unroll
      for (int t = 0; t < 4; ++t) {
        acc[t][0] = __builtin_amdgcn_mfma_f32_16x16x32_f16(aC[t], bC0, acc[t][0], 0, 0, 0);
        acc[t][1] = __builtin_amdgcn_mfma_f32_16x16x32_f16(aC[t], bC1, acc[t][1], 0, 0, 0);
      }
      // rotate pipeline (guards are compile-time; no uninitialized reads)
      if (ko + 1 < KOFF) {
#pragma unroll
        for (int t = 0; t < 4; ++t) aC[t] = aN[t];
        bC0 = bN0; bC1 = bN1;
      }
      if (ko + 2 < KOFF) {
#pragma unroll
        for (int t = 0; t < 4; ++t) ivB[t] = ivN[t];
      }
    }
  }

  // ---- epilogue: y store + fused BN partial sums ----
  float s0 = 0.f, s1 = 0.f, q0 = 0.f, q1 = 0.f;
  if (active) {
#pragma unroll
    for (int t = 0; t < 4; ++t) {
#pragma unroll
      for (int h = 0; h < 2; ++h) {
        floatx4 c = acc[t][h];
        int co = h * 16 + col;
#pragma unroll
        for (int r = 0; r < 4; ++r) {
          int vox = base + t * 16 + quad * 4 + r;
          if (vox < N) {  // defensive (no-op when 64|N)
            y[(size_t)vox * COUT + co] = c[r];
            float v = c[r];
            if (h == 0) { s0 += v; q0 += v * v; }
            else        { s1 += v; q1 += v * v; }
          }
        }
      }
    }
  }
  // reduce across the 4 quads (lanes col, col+16, col+32, col+48)
  s0 += __shfl_xor(s0, 16); s0 += __shfl_xor(s0, 32);
  s1 += __shfl_xor(s1, 16); s1 += __shfl_xor(s1, 32);
  q0 += __shfl_xor(q0, 16); q0 += __shfl_xor(q0, 32);
  q1 += __shfl_xor(q1, 16); q1 += __shfl_xor(q1, 32);
  if (quad == 0) {
    smS[wave * 32 + col] = s0;
    smS[wave * 32 + 16 + col] = s1;
    smQ[wave * 32 + col] = q0;
    smQ[wave * 32 + 16 + col] = q1;
  }
  __syncthreads();
  int tid = threadIdx.x;
  if (tid < 64) {
    int co = tid & 31;
    const float* arr = (tid < 32) ? smS : smQ;
    float s = arr[co] + arr[32 + co] + arr[64 + co] + arr[96 + co];
    atomicAdd(&stats[(tid < 32 ? 0 : 32) + co], s);
  }
}

// BN finalize (per-block, from raw sums) + normalize + ReLU, in place.
__global__ void bn_apply(float* __restrict__ y, const float* __restrict__ stats,
                         const float* __restrict__ gamma,
                         const float* __restrict__ beta, int total4, float invN) {
  __shared__ float sc_sh[64];
  int tid = threadIdx.x;
  if (tid < 32) {
    float mean = stats[tid] * invN;
    float ex2 = stats[32 + tid] * invN;
    float var = ex2 - mean * mean;
    float inv = rsqrtf(var + EPSV);
    float sc = gamma[tid] * inv;
    sc_sh[tid] = sc;
    sc_sh[32 + tid] = beta[tid] - mean * sc;
  }
  __syncthreads();
  int t = blockIdx.x * blockDim.x + tid;
  if (t >= total4) return;
  size_t g = (size_t)t * 4;
  int co = (int)(g & 31);
  floatx4 v = *(const floatx4*)(y + g);
  floatx4 sc = *(const floatx4*)&sc_sh[co];
  floatx4 sh = *(const floatx4*)&sc_sh[32 + co];
  floatx4 o;
#pragma unroll
  for (int j = 0; j < 4; ++j) o[j] = fmaxf(0.f, v[j] * sc[j] + sh[j]);
  __builtin_nontemporal_store(o, (floatx4*)(y + g));
}

extern "C" void kernel_launch(void* const* d_in, const int* in_sizes, int n_in,
                              void* d_out, int out_size, void* d_ws,
                              size_t ws_size, hipStream_t stream) {
  const float* feats = (const float*)d_in[0];
  const float* W = (const float*)d_in[1];
  const float* gamma = (const float*)d_in[2];
  const float* beta = (const float*)d_in[3];
  const int* nidx = (const int*)d_in[4];
  const unsigned char* nmask = (const unsigned char*)d_in[5];
  float* out = (float*)d_out;

  int N = in_sizes[0] / CIN;  // 1,000,000

  char* ws = (char*)d_ws;
  size_t f16_bytes = (size_t)(N + 1) * CIN * sizeof(_Float16);  // +1 zero row
  _Float16* f16 = (_Float16*)ws;
  _Float16* wp = (_Float16*)(ws + f16_bytes);
  size_t wp_bytes = (size_t)KOFF * 2 * 64 * 8 * sizeof(_Float16);
  size_t stats_off = ((f16_bytes + wp_bytes + 511) / 512) * 512;
  float* stats = (float*)(ws + stats_off);
  int* flag = (int*)(stats + 64);
  size_t mpack_off = ((stats_off + 768 + 255) / 256) * 256;
  unsigned int* mpack = (unsigned int*)(ws + mpack_off);

  hipMemsetAsync(stats, 0, 65 * sizeof(float), stream);

  setup_k<<<KOFF + 1, 128, 0, stream>>>(W, wp, nmask, flag);

  int total8 = N * CIN / 8;
  int cvtBlocks = (total8 + 4 + 255) / 256;  // +4 half8 stores for zero row
  int mkBlocks = (N + 255) / 256;
  prep_k<<<cvtBlocks + mkBlocks, 256, 0, stream>>>(feats, f16, total8, nmask,
                                                   flag, mpack, N, cvtBlocks);

  int nwaves = (N + 63) / 64;
  int nblocks = (nwaves + 3) / 4;
  conv_mfma_d<<<nblocks, 256, 0, stream>>>(f16, wp, nidx, mpack, out, stats, N);

  int total4 = N * COUT / 4;
  bn_apply<<<(total4 + 255) / 256, 256, 0, stream>>>(out, stats, gamma, beta,
                                                     total4, 1.0f / (float)N);
}

// Round 4
// 623.056 us; speedup vs baseline: 1.1733x; 1.0967x over previous
//
#include <hip/hip_runtime.h>

typedef _Float16 half8 __attribute__((ext_vector_type(8)));
typedef float floatx4 __attribute__((ext_vector_type(4)));

#define CIN 32
#define COUT 32
#define KOFF 27
#define EPSV 1e-5f

// ---------------------------------------------------------------------------
// ws layout:
//   [0, (N+1)*32*2)        feats16 (f16 copy of feats + zero row at index N)
//   [+, +55296)            Wpack: B-fragments, f16
//   [align 512, +768)      stats: sum[32], sumsq[32], flag
// conv stages idx|maskbit into LDS per wave (coalesced int4 fill), so the
// hot loop has ONLY the 4 A-gathers + 2 B loads as VMEM; idx comes from
// conflict-free ds_read (stride 27 words, gcd(27,32)=1). Invalid neighbors
// redirect to the L1-hot zero row at index N -> gathers are unconditional.
// Dispatches: memset, setup(pack_w+detect), prep(cvt+zero-row),
//             conv(+fused BN stats), bn_apply(+inline finalize).
// ---------------------------------------------------------------------------

// blocks 0..26: pack W fragments; block 27: detect mask dtype.
__global__ void setup_k(const float* __restrict__ W, _Float16* __restrict__ wp,
                        const unsigned char* __restrict__ m,
                        int* __restrict__ flag) {
  if (blockIdx.x < KOFF) {
    int ko = blockIdx.x;
    int h = threadIdx.x >> 6;        // 128 threads: 2 halves
    int lane = threadIdx.x & 63;
    int col = lane & 15, quad = lane >> 4;
    half8 p;
#pragma unroll
    for (int j = 0; j < 8; ++j) {
      int k = quad * 8 + j;
      p[j] = (_Float16)W[(ko * CIN + k) * COUT + h * 16 + col];
    }
    *(half8*)(wp + ((size_t)(ko * 2 + h) * 64 + lane) * 8) = p;
  } else {
    // int32 mask => bytes at offset%4!=0 all zero; byte mask => ~50% nonzero
    int tid = threadIdx.x;
    int any = 0;
    for (int i = tid; i < 4096; i += 128) {
      if ((i & 3) != 0 && m[i] != 0) any = 1;
    }
    if (any) atomicOr(flag, 1);
  }
}

// feats fp32->f16 (+ zero row at index N).
__global__ void prep_k(const float* __restrict__ feats,
                       _Float16* __restrict__ f16, int total8) {
  int t = blockIdx.x * 256 + threadIdx.x;
  if (t < total8) {
    const floatx4* in4 = (const floatx4*)feats;
    floatx4 a = __builtin_nontemporal_load(&in4[(size_t)t * 2]);
    floatx4 b = __builtin_nontemporal_load(&in4[(size_t)t * 2 + 1]);
    half8 h;
    h[0] = (_Float16)a[0]; h[1] = (_Float16)a[1];
    h[2] = (_Float16)a[2]; h[3] = (_Float16)a[3];
    h[4] = (_Float16)b[0]; h[5] = (_Float16)b[1];
    h[6] = (_Float16)b[2]; h[7] = (_Float16)b[3];
    *(half8*)(f16 + (size_t)t * 8) = h;  // temporal: keep cache-resident
  } else if (t < total8 + 4) {
    half8 z;
#pragma unroll
    for (int j = 0; j < 8; ++j) z[j] = (_Float16)0.f;
    *(half8*)(f16 + (size_t)t * 8) = z;  // zero row at voxel index N
  }
}

__launch_bounds__(256, 4)
__global__ void conv_mfma_l(const _Float16* __restrict__ f16,
                            const _Float16* __restrict__ wp,
                            const int* __restrict__ nidx,
                            const unsigned char* __restrict__ nmask,
                            const int* __restrict__ flagp,
                            float* __restrict__ y,
                            float* __restrict__ stats, int N) {
  __shared__ int lidx[4 * 64 * KOFF];   // per-wave [64][27] idx|maskbit
  __shared__ float smS[4 * 32];
  __shared__ float smQ[4 * 32];
  int wave = threadIdx.x >> 6;
  int lane = threadIdx.x & 63;
  int base = (blockIdx.x * 4 + wave) * 64;
  bool active = base < N;
  int col = lane & 15, quad = lane >> 4;
  const half8* wfrag = (const half8*)wp;
  const _Float16* fq = f16 + quad * 8;  // per-quad 16B slice of a 64B row
  int* lw = lidx + wave * (64 * KOFF);

  floatx4 acc[4][2];
#pragma unroll
  for (int t = 0; t < 4; ++t)
#pragma unroll
    for (int h = 0; h < 2; ++h) {
      acc[t][h][0] = 0.f; acc[t][h][1] = 0.f;
      acc[t][h][2] = 0.f; acc[t][h][3] = 0.f;
    }

  if (active) {
    bool bytemode = (*flagp != 0);
    int nv = N - base; if (nv > 64) nv = 64;
    if (nv == 64) {
      // coalesced fill: 1728 ints = 432 int4
      const int4* gi = (const int4*)(nidx + (size_t)base * KOFF);
      const int4* gm4 = (const int4*)((const int*)nmask + (size_t)base * KOFF);
      const unsigned int* gmb = (const unsigned int*)(nmask + (size_t)base * KOFF);
#pragma unroll
      for (int s = 0; s < 7; ++s) {
        int id4 = s * 64 + lane;
        if (id4 < 432) {
          int4 iv = gi[id4];
          unsigned int m0, m1, m2, m3;
          if (bytemode) {
            unsigned int mw = gmb[id4];
            m0 = mw & 0xffu; m1 = mw & 0xff00u;
            m2 = mw & 0xff0000u; m3 = mw & 0xff000000u;
          } else {
            int4 mv = gm4[id4];
            m0 = (unsigned int)mv.x; m1 = (unsigned int)mv.y;
            m2 = (unsigned int)mv.z; m3 = (unsigned int)mv.w;
          }
          int4 ov;
          ov.x = (iv.x & 0x7FFFFFFF) | (m0 ? (int)0x80000000 : 0);
          ov.y = (iv.y & 0x7FFFFFFF) | (m1 ? (int)0x80000000 : 0);
          ov.z = (iv.z & 0x7FFFFFFF) | (m2 ? (int)0x80000000 : 0);
          ov.w = (iv.w & 0x7FFFFFFF) | (m3 ? (int)0x80000000 : 0);
          *(int4*)(lw + id4 * 4) = ov;
        }
      }
    } else {
      // guarded tail fill
      int total = nv * KOFF;
      for (int p = lane; p < total; p += 64) {
        size_t g = (size_t)base * KOFF + p;
        int iv = nidx[g];
        int mk = bytemode ? (int)nmask[g] : ((const int*)nmask)[g];
        lw[p] = (iv & 0x7FFFFFFF) | (mk ? (int)0x80000000 : 0);
      }
      for (int p = nv * KOFF + lane; p < 64 * KOFF; p += 64) lw[p] = 0;
    }
    // no barrier: each wave reads only its own LDS region

    // prologue: idx(0) -> aC gathers; idx(1) -> ivB
    half8 aC[4];
    int ivB[4];
#pragma unroll
    for (int t = 0; t < 4; ++t) {
      int v0 = lw[(t * 16 + col) * KOFF + 0];
      int sel = (v0 < 0) ? (v0 & 0x7FFFFFFF) : N;
      aC[t] = *(const half8*)(fq + ((size_t)sel << 5));
      ivB[t] = lw[(t * 16 + col) * KOFF + 1];
    }
    half8 bC0 = wfrag[lane];
    half8 bC1 = wfrag[64 + lane];

#pragma unroll
    for (int ko = 0; ko < KOFF; ++ko) {
      half8 aN[4];
      half8 bN0, bN1;
      int ivN[4];
      if (ko + 1 < KOFF) {
        bN0 = wfrag[(size_t)((ko + 1) * 2 + 0) * 64 + lane];
        bN1 = wfrag[(size_t)((ko + 1) * 2 + 1) * 64 + lane];
#pragma unroll
        for (int t = 0; t < 4; ++t) {
          int v = ivB[t];
          int sel = (v < 0) ? (v & 0x7FFFFFFF) : N;
          aN[t] = *(const half8*)(fq + ((size_t)sel << 5));
        }
      }
      if (ko + 2 < KOFF) {
#pragma unroll
        for (int t = 0; t < 4; ++t)
          ivN[t] = lw[(t * 16 + col) * KOFF + ko + 2];
      }
#pragma unroll
      for (int t = 0; t < 4; ++t) {
        acc[t][0] = __builtin_amdgcn_mfma_f32_16x16x32_f16(aC[t], bC0, acc[t][0], 0, 0, 0);
        acc[t][1] = __builtin_amdgcn_mfma_f32_16x16x32_f16(aC[t], bC1, acc[t][1], 0, 0, 0);
      }
      if (ko + 1 < KOFF) {
#pragma unroll
        for (int t = 0; t < 4; ++t) aC[t] = aN[t];
        bC0 = bN0; bC1 = bN1;
      }
      if (ko + 2 < KOFF) {
#pragma unroll
        for (int t = 0; t < 4; ++t) ivB[t] = ivN[t];
      }
    }
  }

  // ---- epilogue: y store + fused BN partial sums ----
  float s0 = 0.f, s1 = 0.f, q0 = 0.f, q1 = 0.f;
  if (active) {
#pragma unroll
    for (int t = 0; t < 4; ++t) {
#pragma unroll
      for (int h = 0; h < 2; ++h) {
        floatx4 c = acc[t][h];
        int co = h * 16 + col;
#pragma unroll
        for (int r = 0; r < 4; ++r) {
          int vox = base + t * 16 + quad * 4 + r;
          if (vox < N) {  // no-op when 64|N
            y[(size_t)vox * COUT + co] = c[r];
            float v = c[r];
            if (h == 0) { s0 += v; q0 += v * v; }
            else        { s1 += v; q1 += v * v; }
          }
        }
      }
    }
  }
  // reduce across the 4 quads (lanes col, col+16, col+32, col+48)
  s0 += __shfl_xor(s0, 16); s0 += __shfl_xor(s0, 32);
  s1 += __shfl_xor(s1, 16); s1 += __shfl_xor(s1, 32);
  q0 += __shfl_xor(q0, 16); q0 += __shfl_xor(q0, 32);
  q1 += __shfl_xor(q1, 16); q1 += __shfl_xor(q1, 32);
  if (quad == 0) {
    smS[wave * 32 + col] = s0;
    smS[wave * 32 + 16 + col] = s1;
    smQ[wave * 32 + col] = q0;
    smQ[wave * 32 + 16 + col] = q1;
  }
  __syncthreads();
  int tid = threadIdx.x;
  if (tid < 64) {
    int co = tid & 31;
    const float* arr = (tid < 32) ? smS : smQ;
    float s = arr[co] + arr[32 + co] + arr[64 + co] + arr[96 + co];
    atomicAdd(&stats[(tid < 32 ? 0 : 32) + co], s);
  }
}

// BN finalize (per-block, from raw sums) + normalize + ReLU, in place.
__global__ void bn_apply(float* __restrict__ y, const float* __restrict__ stats,
                         const float* __restrict__ gamma,
                         const float* __restrict__ beta, int total4, float invN) {
  __shared__ float sc_sh[64];
  int tid = threadIdx.x;
  if (tid < 32) {
    float mean = stats[tid] * invN;
    float ex2 = stats[32 + tid] * invN;
    float var = ex2 - mean * mean;
    float inv = rsqrtf(var + EPSV);
    float sc = gamma[tid] * inv;
    sc_sh[tid] = sc;
    sc_sh[32 + tid] = beta[tid] - mean * sc;
  }
  __syncthreads();
  int t = blockIdx.x * blockDim.x + tid;
  if (t >= total4) return;
  size_t g = (size_t)t * 4;
  int co = (int)(g & 31);
  floatx4 v = *(const floatx4*)(y + g);
  floatx4 sc = *(const floatx4*)&sc_sh[co];
  floatx4 sh = *(const floatx4*)&sc_sh[32 + co];
  floatx4 o;
#pragma unroll
  for (int j = 0; j < 4; ++j) o[j] = fmaxf(0.f, v[j] * sc[j] + sh[j]);
  __builtin_nontemporal_store(o, (floatx4*)(y + g));
}

extern "C" void kernel_launch(void* const* d_in, const int* in_sizes, int n_in,
                              void* d_out, int out_size, void* d_ws,
                              size_t ws_size, hipStream_t stream) {
  const float* feats = (const float*)d_in[0];
  const float* W = (const float*)d_in[1];
  const float* gamma = (const float*)d_in[2];
  const float* beta = (const float*)d_in[3];
  const int* nidx = (const int*)d_in[4];
  const unsigned char* nmask = (const unsigned char*)d_in[5];
  float* out = (float*)d_out;

  int N = in_sizes[0] / CIN;  // 1,000,000

  char* ws = (char*)d_ws;
  size_t f16_bytes = (size_t)(N + 1) * CIN * sizeof(_Float16);  // +1 zero row
  _Float16* f16 = (_Float16*)ws;
  _Float16* wp = (_Float16*)(ws + f16_bytes);
  size_t wp_bytes = (size_t)KOFF * 2 * 64 * 8 * sizeof(_Float16);
  size_t stats_off = ((f16_bytes + wp_bytes + 511) / 512) * 512;
  float* stats = (float*)(ws + stats_off);
  int* flag = (int*)(stats + 64);

  hipMemsetAsync(stats, 0, 65 * sizeof(float), stream);

  setup_k<<<KOFF + 1, 128, 0, stream>>>(W, wp, nmask, flag);

  int total8 = N * CIN / 8;
  int cvtBlocks = (total8 + 4 + 255) / 256;  // +4 half8 stores for zero row
  prep_k<<<cvtBlocks, 256, 0, stream>>>(feats, f16, total8);

  int nwaves = (N + 63) / 64;
  int nblocks = (nwaves + 3) / 4;
  conv_mfma_l<<<nblocks, 256, 0, stream>>>(f16, wp, nidx, nmask, flag, out,
                                           stats, N);

  int total4 = N * COUT / 4;
  bn_apply<<<(total4 + 255) / 256, 256, 0, stream>>>(out, stats, gamma, beta,
                                                     total4, 1.0f / (float)N);
}

// Round 5
// 615.122 us; speedup vs baseline: 1.1885x; 1.0129x over previous
//
#include <hip/hip_runtime.h>

typedef _Float16 half8 __attribute__((ext_vector_type(8)));
typedef float floatx4 __attribute__((ext_vector_type(4)));

#define CIN 32
#define COUT 32
#define KOFF 27
#define EPSV 1e-5f

// ---------------------------------------------------------------------------
// ws layout:
//   [0, (N+1)*32*2)        feats16 (f16 copy of feats + zero row at index N)
//   [+, +55296)            Wpack: B-fragments, f16
//   [align 512, +768)      stats: sum[32], sumsq[32], flag
// conv: per-wave LDS idx table + QUARTER-WAVE-COALESCED gathers:
//   gather instr i: lane l reads chunk (l&3) of row voxel 16i+(l>>2)
//   -> each 16-lane quarter touches 4 contiguous 64B rows (4 lines) instead
//      of 16 random lines: 4x fewer L1/TA tag cycles (the measured wall).
//   Rows round-trip through a per-wave 4KB LDS stage (XOR swizzle
//   chunk' = c ^ ((v ^ v>>2)&3), <=2-way bank alias on write and read),
//   then ds_read_b128 back as MFMA A-fragments. Invalid neighbors redirect
//   to the L1-hot zero row at index N (gathers unconditional).
// Dispatches: memset, setup(pack_w+detect), prep(cvt+zero-row),
//             conv(+fused BN stats), bn_apply(+inline finalize).
// ---------------------------------------------------------------------------

// blocks 0..26: pack W fragments; block 27: detect mask dtype.
__global__ void setup_k(const float* __restrict__ W, _Float16* __restrict__ wp,
                        const unsigned char* __restrict__ m,
                        int* __restrict__ flag) {
  if (blockIdx.x < KOFF) {
    int ko = blockIdx.x;
    int h = threadIdx.x >> 6;        // 128 threads: 2 halves
    int lane = threadIdx.x & 63;
    int col = lane & 15, quad = lane >> 4;
    half8 p;
#pragma unroll
    for (int j = 0; j < 8; ++j) {
      int k = quad * 8 + j;
      p[j] = (_Float16)W[(ko * CIN + k) * COUT + h * 16 + col];
    }
    *(half8*)(wp + ((size_t)(ko * 2 + h) * 64 + lane) * 8) = p;
  } else {
    // int32 mask => bytes at offset%4!=0 all zero; byte mask => ~50% nonzero
    int tid = threadIdx.x;
    int any = 0;
    for (int i = tid; i < 4096; i += 128) {
      if ((i & 3) != 0 && m[i] != 0) any = 1;
    }
    if (any) atomicOr(flag, 1);
  }
}

// feats fp32->f16 (+ zero row at index N).
__global__ void prep_k(const float* __restrict__ feats,
                       _Float16* __restrict__ f16, int total8) {
  int t = blockIdx.x * 256 + threadIdx.x;
  if (t < total8) {
    const floatx4* in4 = (const floatx4*)feats;
    floatx4 a = __builtin_nontemporal_load(&in4[(size_t)t * 2]);
    floatx4 b = __builtin_nontemporal_load(&in4[(size_t)t * 2 + 1]);
    half8 h;
    h[0] = (_Float16)a[0]; h[1] = (_Float16)a[1];
    h[2] = (_Float16)a[2]; h[3] = (_Float16)a[3];
    h[4] = (_Float16)b[0]; h[5] = (_Float16)b[1];
    h[6] = (_Float16)b[2]; h[7] = (_Float16)b[3];
    *(half8*)(f16 + (size_t)t * 8) = h;  // temporal: keep cache-resident
  } else if (t < total8 + 4) {
    half8 z;
#pragma unroll
    for (int j = 0; j < 8; ++j) z[j] = (_Float16)0.f;
    *(half8*)(f16 + (size_t)t * 8) = z;  // zero row at voxel index N
  }
}

__launch_bounds__(256, 3)
__global__ void conv_mfma_q(const _Float16* __restrict__ f16,
                            const _Float16* __restrict__ wp,
                            const int* __restrict__ nidx,
                            const unsigned char* __restrict__ nmask,
                            const int* __restrict__ flagp,
                            float* __restrict__ y,
                            float* __restrict__ stats, int N) {
  __shared__ int lidx[4 * 64 * KOFF];        // per-wave [64][27] idx|maskbit
  __shared__ _Float16 sstage[4 * 64 * 32];   // per-wave 64 rows x 32 halves
  __shared__ float smS[4 * 32];
  __shared__ float smQ[4 * 32];
  int wave = threadIdx.x >> 6;
  int lane = threadIdx.x & 63;
  int base = (blockIdx.x * 4 + wave) * 64;
  bool active = base < N;
  int col = lane & 15, quad = lane >> 4;
  const half8* wfrag = (const half8*)wp;
  int* lw = lidx + wave * (64 * KOFF);
  _Float16* stg = sstage + wave * (64 * 32);

  floatx4 acc[4][2];
#pragma unroll
  for (int t = 0; t < 4; ++t)
#pragma unroll
    for (int h = 0; h < 2; ++h) {
      acc[t][h][0] = 0.f; acc[t][h][1] = 0.f;
      acc[t][h][2] = 0.f; acc[t][h][3] = 0.f;
    }

  if (active) {
    bool bytemode = (*flagp != 0);
    int nv = N - base; if (nv > 64) nv = 64;
    if (nv == 64) {
      // coalesced fill: 1728 ints = 432 int4
      const int4* gi = (const int4*)(nidx + (size_t)base * KOFF);
      const int4* gm4 = (const int4*)((const int*)nmask + (size_t)base * KOFF);
      const unsigned int* gmb = (const unsigned int*)(nmask + (size_t)base * KOFF);
#pragma unroll
      for (int s = 0; s < 7; ++s) {
        int id4 = s * 64 + lane;
        if (id4 < 432) {
          int4 iv = gi[id4];
          unsigned int m0, m1, m2, m3;
          if (bytemode) {
            unsigned int mw = gmb[id4];
            m0 = mw & 0xffu; m1 = mw & 0xff00u;
            m2 = mw & 0xff0000u; m3 = mw & 0xff000000u;
          } else {
            int4 mv = gm4[id4];
            m0 = (unsigned int)mv.x; m1 = (unsigned int)mv.y;
            m2 = (unsigned int)mv.z; m3 = (unsigned int)mv.w;
          }
          int4 ov;
          ov.x = (iv.x & 0x7FFFFFFF) | (m0 ? (int)0x80000000 : 0);
          ov.y = (iv.y & 0x7FFFFFFF) | (m1 ? (int)0x80000000 : 0);
          ov.z = (iv.z & 0x7FFFFFFF) | (m2 ? (int)0x80000000 : 0);
          ov.w = (iv.w & 0x7FFFFFFF) | (m3 ? (int)0x80000000 : 0);
          *(int4*)(lw + id4 * 4) = ov;
        }
      }
    } else {
      // guarded tail fill
      int total = nv * KOFF;
      for (int p = lane; p < total; p += 64) {
        size_t g = (size_t)base * KOFF + p;
        int iv = nidx[g];
        int mk = bytemode ? (int)nmask[g] : ((const int*)nmask)[g];
        lw[p] = (iv & 0x7FFFFFFF) | (mk ? (int)0x80000000 : 0);
      }
      for (int p = nv * KOFF + lane; p < 64 * KOFF; p += 64) lw[p] = 0;
    }
    // no barrier: each wave reads only its own LDS region

    // gather lane mapping: instr i covers voxel vg = 16i + (lane>>2), chunk c = lane&3
    int vg_sub = lane >> 2;                 // 0..15
    int cch = lane & 3;
    // stage write swizzle (lane-only): sw = c ^ ((vg^(vg>>2))&3)
    int swz_w = cch ^ ((lane >> 2) & 3) ^ ((lane >> 4) & 3);
    // stage read swizzle: chunk quad of voxel t*16+col stored at quad^(col&3)^(col>>2)
    int swz_r = quad ^ (col & 3) ^ (col >> 2);
    const _Float16* fch = f16 + cch * 8;    // chunk offset within a 64B row

    // ---- prologue: gather ko=0, stage it; prefetch idx for ko=1 ----
    half8 gv[4];
    int ivB[4];
#pragma unroll
    for (int i = 0; i < 4; ++i) {
      int v0 = lw[(16 * i + vg_sub) * KOFF + 0];
      int sel = (v0 < 0) ? (v0 & 0x7FFFFFFF) : N;
      gv[i] = *(const half8*)(fch + ((size_t)sel << 5));
    }
#pragma unroll
    for (int i = 0; i < 4; ++i) ivB[i] = lw[(16 * i + vg_sub) * KOFF + 1];
#pragma unroll
    for (int i = 0; i < 4; ++i)
      *(half8*)(stg + (16 * i + vg_sub) * 32 + swz_w * 8) = gv[i];

#pragma unroll
    for (int ko = 0; ko < KOFF; ++ko) {
      // R(ko): A-fragments from stage (in-order LDS: W(ko) precedes)
      half8 aC[4];
#pragma unroll
      for (int t = 0; t < 4; ++t)
        aC[t] = *(const half8*)(stg + (t * 16 + col) * 32 + swz_r * 8);
      // B(ko): L1-hot
      half8 bC0 = wfrag[(size_t)(ko * 2 + 0) * 64 + lane];
      half8 bC1 = wfrag[(size_t)(ko * 2 + 1) * 64 + lane];
      // G(ko+1): coalesced gathers (stay in flight across the MFMAs)
      if (ko + 1 < KOFF) {
#pragma unroll
        for (int i = 0; i < 4; ++i) {
          int v = ivB[i];
          int sel = (v < 0) ? (v & 0x7FFFFFFF) : N;
          gv[i] = *(const half8*)(fch + ((size_t)sel << 5));
        }
      }
      // idx prefetch for ko+2
      if (ko + 2 < KOFF) {
        int ivN[4];
#pragma unroll
        for (int i = 0; i < 4; ++i)
          ivN[i] = lw[(16 * i + vg_sub) * KOFF + ko + 2];
#pragma unroll
        for (int i = 0; i < 4; ++i) ivB[i] = ivN[i];
      }
      // M(ko)
#pragma unroll
      for (int t = 0; t < 4; ++t) {
        acc[t][0] = __builtin_amdgcn_mfma_f32_16x16x32_f16(aC[t], bC0, acc[t][0], 0, 0, 0);
        acc[t][1] = __builtin_amdgcn_mfma_f32_16x16x32_f16(aC[t], bC1, acc[t][1], 0, 0, 0);
      }
      // W(ko+1): single buffer is safe (R(ko) precedes in program order)
      if (ko + 1 < KOFF) {
#pragma unroll
        for (int i = 0; i < 4; ++i)
          *(half8*)(stg + (16 * i + vg_sub) * 32 + swz_w * 8) = gv[i];
      }
    }
  }

  // ---- epilogue: y store + fused BN partial sums ----
  float s0 = 0.f, s1 = 0.f, q0 = 0.f, q1 = 0.f;
  if (active) {
#pragma unroll
    for (int t = 0; t < 4; ++t) {
#pragma unroll
      for (int h = 0; h < 2; ++h) {
        floatx4 c = acc[t][h];
        int co = h * 16 + col;
#pragma unroll
        for (int r = 0; r < 4; ++r) {
          int vox = base + t * 16 + quad * 4 + r;
          if (vox < N) {  // no-op when 64|N
            y[(size_t)vox * COUT + co] = c[r];
            float v = c[r];
            if (h == 0) { s0 += v; q0 += v * v; }
            else        { s1 += v; q1 += v * v; }
          }
        }
      }
    }
  }
  // reduce across the 4 quads (lanes col, col+16, col+32, col+48)
  s0 += __shfl_xor(s0, 16); s0 += __shfl_xor(s0, 32);
  s1 += __shfl_xor(s1, 16); s1 += __shfl_xor(s1, 32);
  q0 += __shfl_xor(q0, 16); q0 += __shfl_xor(q0, 32);
  q1 += __shfl_xor(q1, 16); q1 += __shfl_xor(q1, 32);
  if (quad == 0) {
    smS[wave * 32 + col] = s0;
    smS[wave * 32 + 16 + col] = s1;
    smQ[wave * 32 + col] = q0;
    smQ[wave * 32 + 16 + col] = q1;
  }
  __syncthreads();
  int tid = threadIdx.x;
  if (tid < 64) {
    int co = tid & 31;
    const float* arr = (tid < 32) ? smS : smQ;
    float s = arr[co] + arr[32 + co] + arr[64 + co] + arr[96 + co];
    atomicAdd(&stats[(tid < 32 ? 0 : 32) + co], s);
  }
}

// BN finalize (per-block, from raw sums) + normalize + ReLU, in place.
__global__ void bn_apply(float* __restrict__ y, const float* __restrict__ stats,
                         const float* __restrict__ gamma,
                         const float* __restrict__ beta, int total4, float invN) {
  __shared__ float sc_sh[64];
  int tid = threadIdx.x;
  if (tid < 32) {
    float mean = stats[tid] * invN;
    float ex2 = stats[32 + tid] * invN;
    float var = ex2 - mean * mean;
    float inv = rsqrtf(var + EPSV);
    float sc = gamma[tid] * inv;
    sc_sh[tid] = sc;
    sc_sh[32 + tid] = beta[tid] - mean * sc;
  }
  __syncthreads();
  int t = blockIdx.x * blockDim.x + tid;
  if (t >= total4) return;
  size_t g = (size_t)t * 4;
  int co = (int)(g & 31);
  floatx4 v = *(const floatx4*)(y + g);
  floatx4 sc = *(const floatx4*)&sc_sh[co];
  floatx4 sh = *(const floatx4*)&sc_sh[32 + co];
  floatx4 o;
#pragma unroll
  for (int j = 0; j < 4; ++j) o[j] = fmaxf(0.f, v[j] * sc[j] + sh[j]);
  __builtin_nontemporal_store(o, (floatx4*)(y + g));
}

extern "C" void kernel_launch(void* const* d_in, const int* in_sizes, int n_in,
                              void* d_out, int out_size, void* d_ws,
                              size_t ws_size, hipStream_t stream) {
  const float* feats = (const float*)d_in[0];
  const float* W = (const float*)d_in[1];
  const float* gamma = (const float*)d_in[2];
  const float* beta = (const float*)d_in[3];
  const int* nidx = (const int*)d_in[4];
  const unsigned char* nmask = (const unsigned char*)d_in[5];
  float* out = (float*)d_out;

  int N = in_sizes[0] / CIN;  // 1,000,000

  char* ws = (char*)d_ws;
  size_t f16_bytes = (size_t)(N + 1) * CIN * sizeof(_Float16);  // +1 zero row
  _Float16* f16 = (_Float16*)ws;
  _Float16* wp = (_Float16*)(ws + f16_bytes);
  size_t wp_bytes = (size_t)KOFF * 2 * 64 * 8 * sizeof(_Float16);
  size_t stats_off = ((f16_bytes + wp_bytes + 511) / 512) * 512;
  float* stats = (float*)(ws + stats_off);
  int* flag = (int*)(stats + 64);

  hipMemsetAsync(stats, 0, 65 * sizeof(float), stream);

  setup_k<<<KOFF + 1, 128, 0, stream>>>(W, wp, nmask, flag);

  int total8 = N * CIN / 8;
  int cvtBlocks = (total8 + 4 + 255) / 256;  // +4 half8 stores for zero row
  prep_k<<<cvtBlocks, 256, 0, stream>>>(feats, f16, total8);

  int nwaves = (N + 63) / 64;
  int nblocks = (nwaves + 3) / 4;
  conv_mfma_q<<<nblocks, 256, 0, stream>>>(f16, wp, nidx, nmask, flag, out,
                                           stats, N);

  int total4 = N * COUT / 4;
  bn_apply<<<(total4 + 255) / 256, 256, 0, stream>>>(out, stats, gamma, beta,
                                                     total4, 1.0f / (float)N);
}

// Round 7
// 608.283 us; speedup vs baseline: 1.2018x; 1.0112x over previous
//
#include <hip/hip_runtime.h>

typedef _Float16 half8 __attribute__((ext_vector_type(8)));
typedef float floatx4 __attribute__((ext_vector_type(4)));
typedef int intx4 __attribute__((ext_vector_type(4)));

#define CIN 32
#define COUT 32
#define KOFF 27
#define EPSV 1e-5f

// ---------------------------------------------------------------------------
// ws layout:
//   [0, (N+1)*32*2)        feats16 (f16 copy of feats + zero row at index N)
//   [+, +55296)            Wpack: B-fragments, f16
//   [align 512, +768)      stats: sum[32], sumsq[32], flag
//   [align 256, +N*32*2)   y16: pre-BN conv output in f16
// conv is at the random-64B-gather memory roofline (~3.5 TB/s L2-miss level,
// measured invariant across 4 gather structures) -> this round attacks
// everything else: 3 graph nodes total (fused setup+prep, conv, bn),
// f16 y (halves conv write + bn read), nontemporal idx/mask streams.
// ---------------------------------------------------------------------------

// blocks [0,KOFF): pack W fragments (128 threads used).
// block KOFF: detect mask dtype, zero stats+flag.
// blocks (KOFF, ...]: feats fp32->f16 (+ zero row at index N).
__global__ void fused_prep(const float* __restrict__ feats,
                           _Float16* __restrict__ f16, int total8,
                           const float* __restrict__ W,
                           _Float16* __restrict__ wp,
                           const unsigned char* __restrict__ m,
                           int* __restrict__ flag,
                           float* __restrict__ stats) {
  int bx = blockIdx.x;
  int tid = threadIdx.x;
  if (bx < KOFF) {
    if (tid < 128) {
      int ko = bx;
      int h = tid >> 6;        // 2 halves
      int lane = tid & 63;
      int col = lane & 15, quad = lane >> 4;
      half8 p;
#pragma unroll
      for (int j = 0; j < 8; ++j) {
        int k = quad * 8 + j;
        p[j] = (_Float16)W[(ko * CIN + k) * COUT + h * 16 + col];
      }
      *(half8*)(wp + ((size_t)(ko * 2 + h) * 64 + lane) * 8) = p;
    }
    return;
  }
  if (bx == KOFF) {
    // int32 mask => bytes at offset%4!=0 all zero; byte mask => ~50% nonzero
    __shared__ int red;
    if (tid == 0) red = 0;
    __syncthreads();
    int any = 0;
    for (int i = tid; i < 4096; i += 256) {
      if ((i & 3) != 0 && m[i] != 0) any = 1;
    }
    if (any) atomicOr(&red, 1);
    __syncthreads();
    if (tid == 0) *flag = red;
    if (tid < 64) stats[tid] = 0.f;
    return;
  }
  int t = (bx - KOFF - 1) * 256 + tid;
  if (t < total8) {
    const floatx4* in4 = (const floatx4*)feats;
    floatx4 a = __builtin_nontemporal_load(&in4[(size_t)t * 2]);
    floatx4 b = __builtin_nontemporal_load(&in4[(size_t)t * 2 + 1]);
    half8 h;
    h[0] = (_Float16)a[0]; h[1] = (_Float16)a[1];
    h[2] = (_Float16)a[2]; h[3] = (_Float16)a[3];
    h[4] = (_Float16)b[0]; h[5] = (_Float16)b[1];
    h[6] = (_Float16)b[2]; h[7] = (_Float16)b[3];
    *(half8*)(f16 + (size_t)t * 8) = h;  // temporal: keep L3-resident
  } else if (t < total8 + 4) {
    half8 z;
#pragma unroll
    for (int j = 0; j < 8; ++j) z[j] = (_Float16)0.f;
    *(half8*)(f16 + (size_t)t * 8) = z;  // zero row at voxel index N
  }
}

__launch_bounds__(256, 4)
__global__ void conv_mfma_l(const _Float16* __restrict__ f16,
                            const _Float16* __restrict__ wp,
                            const int* __restrict__ nidx,
                            const unsigned char* __restrict__ nmask,
                            const int* __restrict__ flagp,
                            _Float16* __restrict__ y16,
                            float* __restrict__ stats, int N) {
  __shared__ int lidx[4 * 64 * KOFF];   // per-wave [64][27] idx|maskbit
  __shared__ float smS[4 * 32];
  __shared__ float smQ[4 * 32];
  int wave = threadIdx.x >> 6;
  int lane = threadIdx.x & 63;
  int base = (blockIdx.x * 4 + wave) * 64;
  bool active = base < N;
  int col = lane & 15, quad = lane >> 4;
  const half8* wfrag = (const half8*)wp;
  const _Float16* fq = f16 + quad * 8;  // per-quad 16B slice of a 64B row
  int* lw = lidx + wave * (64 * KOFF);

  floatx4 acc[4][2];
#pragma unroll
  for (int t = 0; t < 4; ++t)
#pragma unroll
    for (int h = 0; h < 2; ++h) {
      acc[t][h][0] = 0.f; acc[t][h][1] = 0.f;
      acc[t][h][2] = 0.f; acc[t][h][3] = 0.f;
    }

  if (active) {
    bool bytemode = (*flagp != 0);
    int nv = N - base; if (nv > 64) nv = 64;
    if (nv == 64) {
      // coalesced fill: 1728 ints = 432 int4 (nontemporal: single-use streams)
      const intx4* gi = (const intx4*)(nidx + (size_t)base * KOFF);
      const intx4* gm4 = (const intx4*)((const int*)nmask + (size_t)base * KOFF);
      const unsigned int* gmb = (const unsigned int*)(nmask + (size_t)base * KOFF);
#pragma unroll
      for (int s = 0; s < 7; ++s) {
        int id4 = s * 64 + lane;
        if (id4 < 432) {
          intx4 iv = __builtin_nontemporal_load(&gi[id4]);
          unsigned int m0, m1, m2, m3;
          if (bytemode) {
            unsigned int mw = __builtin_nontemporal_load(&gmb[id4]);
            m0 = mw & 0xffu; m1 = mw & 0xff00u;
            m2 = mw & 0xff0000u; m3 = mw & 0xff000000u;
          } else {
            intx4 mv = __builtin_nontemporal_load(&gm4[id4]);
            m0 = (unsigned int)mv.x; m1 = (unsigned int)mv.y;
            m2 = (unsigned int)mv.z; m3 = (unsigned int)mv.w;
          }
          intx4 ov;
          ov.x = (iv.x & 0x7FFFFFFF) | (m0 ? (int)0x80000000 : 0);
          ov.y = (iv.y & 0x7FFFFFFF) | (m1 ? (int)0x80000000 : 0);
          ov.z = (iv.z & 0x7FFFFFFF) | (m2 ? (int)0x80000000 : 0);
          ov.w = (iv.w & 0x7FFFFFFF) | (m3 ? (int)0x80000000 : 0);
          *(intx4*)(lw + id4 * 4) = ov;
        }
      }
    } else {
      // guarded tail fill
      int total = nv * KOFF;
      for (int p = lane; p < total; p += 64) {
        size_t g = (size_t)base * KOFF + p;
        int iv = nidx[g];
        int mk = bytemode ? (int)nmask[g] : ((const int*)nmask)[g];
        lw[p] = (iv & 0x7FFFFFFF) | (mk ? (int)0x80000000 : 0);
      }
      for (int p = nv * KOFF + lane; p < 64 * KOFF; p += 64) lw[p] = 0;
    }
    // no barrier: each wave reads only its own LDS region

    // prologue: idx(0) -> aC gathers; idx(1) -> ivB
    half8 aC[4];
    int ivB[4];
#pragma unroll
    for (int t = 0; t < 4; ++t) {
      int v0 = lw[(t * 16 + col) * KOFF + 0];
      int sel = (v0 < 0) ? (v0 & 0x7FFFFFFF) : N;
      aC[t] = *(const half8*)(fq + ((size_t)sel << 5));
      ivB[t] = lw[(t * 16 + col) * KOFF + 1];
    }
    half8 bC0 = wfrag[lane];
    half8 bC1 = wfrag[64 + lane];

#pragma unroll
    for (int ko = 0; ko < KOFF; ++ko) {
      half8 aN[4];
      half8 bN0, bN1;
      int ivN[4];
      if (ko + 1 < KOFF) {
        bN0 = wfrag[(size_t)((ko + 1) * 2 + 0) * 64 + lane];
        bN1 = wfrag[(size_t)((ko + 1) * 2 + 1) * 64 + lane];
#pragma unroll
        for (int t = 0; t < 4; ++t) {
          int v = ivB[t];
          int sel = (v < 0) ? (v & 0x7FFFFFFF) : N;
          aN[t] = *(const half8*)(fq + ((size_t)sel << 5));
        }
      }
      if (ko + 2 < KOFF) {
#pragma unroll
        for (int t = 0; t < 4; ++t)
          ivN[t] = lw[(t * 16 + col) * KOFF + ko + 2];
      }
#pragma unroll
      for (int t = 0; t < 4; ++t) {
        acc[t][0] = __builtin_amdgcn_mfma_f32_16x16x32_f16(aC[t], bC0, acc[t][0], 0, 0, 0);
        acc[t][1] = __builtin_amdgcn_mfma_f32_16x16x32_f16(aC[t], bC1, acc[t][1], 0, 0, 0);
      }
      if (ko + 1 < KOFF) {
#pragma unroll
        for (int t = 0; t < 4; ++t) aC[t] = aN[t];
        bC0 = bN0; bC1 = bN1;
      }
      if (ko + 2 < KOFF) {
#pragma unroll
        for (int t = 0; t < 4; ++t) ivB[t] = ivN[t];
      }
    }
  }

  // ---- epilogue: y16 store + fused BN partial sums ----
  float s0 = 0.f, s1 = 0.f, q0 = 0.f, q1 = 0.f;
  if (active) {
#pragma unroll
    for (int t = 0; t < 4; ++t) {
#pragma unroll
      for (int h = 0; h < 2; ++h) {
        floatx4 c = acc[t][h];
        int co = h * 16 + col;
#pragma unroll
        for (int r = 0; r < 4; ++r) {
          int vox = base + t * 16 + quad * 4 + r;
          if (vox < N) {  // no-op when 64|N
            y16[(size_t)vox * COUT + co] = (_Float16)c[r];
            float v = c[r];
            if (h == 0) { s0 += v; q0 += v * v; }
            else        { s1 += v; q1 += v * v; }
          }
        }
      }
    }
  }
  // reduce across the 4 quads (lanes col, col+16, col+32, col+48)
  s0 += __shfl_xor(s0, 16); s0 += __shfl_xor(s0, 32);
  s1 += __shfl_xor(s1, 16); s1 += __shfl_xor(s1, 32);
  q0 += __shfl_xor(q0, 16); q0 += __shfl_xor(q0, 32);
  q1 += __shfl_xor(q1, 16); q1 += __shfl_xor(q1, 32);
  if (quad == 0) {
    smS[wave * 32 + col] = s0;
    smS[wave * 32 + 16 + col] = s1;
    smQ[wave * 32 + col] = q0;
    smQ[wave * 32 + 16 + col] = q1;
  }
  __syncthreads();
  int tid = threadIdx.x;
  if (tid < 64) {
    int co = tid & 31;
    const float* arr = (tid < 32) ? smS : smQ;
    float s = arr[co] + arr[32 + co] + arr[64 + co] + arr[96 + co];
    atomicAdd(&stats[(tid < 32 ? 0 : 32) + co], s);
  }
}

// BN finalize (per-block, from raw sums) + normalize + ReLU: y16 -> out f32.
__global__ void bn_apply(const _Float16* __restrict__ y16,
                         float* __restrict__ out,
                         const float* __restrict__ stats,
                         const float* __restrict__ gamma,
                         const float* __restrict__ beta, int total8,
                         float invN) {
  __shared__ float sc_sh[64];
  int tid = threadIdx.x;
  if (tid < 32) {
    float mean = stats[tid] * invN;
    float ex2 = stats[32 + tid] * invN;
    float var = ex2 - mean * mean;
    float inv = rsqrtf(var + EPSV);
    float sc = gamma[tid] * inv;
    sc_sh[tid] = sc;
    sc_sh[32 + tid] = beta[tid] - mean * sc;
  }
  __syncthreads();
  int t = blockIdx.x * blockDim.x + tid;
  if (t >= total8) return;
  size_t g = (size_t)t * 8;
  int co = (int)(g & 31);
  half8 v = __builtin_nontemporal_load((const half8*)(y16 + g));
  floatx4 sc0 = *(const floatx4*)&sc_sh[co];
  floatx4 sh0 = *(const floatx4*)&sc_sh[32 + co];
  floatx4 sc1 = *(const floatx4*)&sc_sh[co + 4];
  floatx4 sh1 = *(const floatx4*)&sc_sh[32 + co + 4];
  floatx4 o0, o1;
#pragma unroll
  for (int j = 0; j < 4; ++j)
    o0[j] = fmaxf(0.f, (float)v[j] * sc0[j] + sh0[j]);
#pragma unroll
  for (int j = 0; j < 4; ++j)
    o1[j] = fmaxf(0.f, (float)v[4 + j] * sc1[j] + sh1[j]);
  __builtin_nontemporal_store(o0, (floatx4*)(out + g));
  __builtin_nontemporal_store(o1, (floatx4*)(out + g + 4));
}

extern "C" void kernel_launch(void* const* d_in, const int* in_sizes, int n_in,
                              void* d_out, int out_size, void* d_ws,
                              size_t ws_size, hipStream_t stream) {
  const float* feats = (const float*)d_in[0];
  const float* W = (const float*)d_in[1];
  const float* gamma = (const float*)d_in[2];
  const float* beta = (const float*)d_in[3];
  const int* nidx = (const int*)d_in[4];
  const unsigned char* nmask = (const unsigned char*)d_in[5];
  float* out = (float*)d_out;

  int N = in_sizes[0] / CIN;  // 1,000,000

  char* ws = (char*)d_ws;
  size_t f16_bytes = (size_t)(N + 1) * CIN * sizeof(_Float16);  // +1 zero row
  _Float16* f16 = (_Float16*)ws;
  _Float16* wp = (_Float16*)(ws + f16_bytes);
  size_t wp_bytes = (size_t)KOFF * 2 * 64 * 8 * sizeof(_Float16);
  size_t stats_off = ((f16_bytes + wp_bytes + 511) / 512) * 512;
  float* stats = (float*)(ws + stats_off);
  int* flag = (int*)(stats + 64);
  size_t y16_off = ((stats_off + 768 + 255) / 256) * 256;
  _Float16* y16 = (_Float16*)(ws + y16_off);

  int total8 = N * CIN / 8;
  int cvtBlocks = (total8 + 4 + 255) / 256;  // +4 half8 stores for zero row
  fused_prep<<<KOFF + 1 + cvtBlocks, 256, 0, stream>>>(feats, f16, total8, W,
                                                       wp, nmask, flag, stats);

  int nwaves = (N + 63) / 64;
  int nblocks = (nwaves + 3) / 4;
  conv_mfma_l<<<nblocks, 256, 0, stream>>>(f16, wp, nidx, nmask, flag, y16,
                                           stats, N);

  int total8v = N * COUT / 8;
  bn_apply<<<(total8v + 255) / 256, 256, 0, stream>>>(y16, out, stats, gamma,
                                                      beta, total8v,
                                                      1.0f / (float)N);
}